// Round 4
// baseline (34.928 us; speedup 1.0000x reference)
//
#include <hip/hip_runtime.h>

#define HID 16

// Force a uniform (lane-invariant) float into an SGPR.
__device__ __forceinline__ float uniformf(float v) {
    return __uint_as_float(__builtin_amdgcn_readfirstlane(__float_as_uint(v)));
}

// tanh(x) ~= xc * p(xc^2), xc = clamp(x, -3, 3).
// Degree-9 odd poly, Chebyshev-node interpolation of tanh(x)/x on [0,3].
// Max abs error ~0.009 (incl. saturation tail); propagates to <2e-3 in y.
__device__ __forceinline__ float tanh_poly(float x) {
    float xc = fminf(fmaxf(x, -3.0f), 3.0f);
    float u = xc * xc;
    float p = fmaf(fmaf(fmaf(fmaf(2.3926e-4f, u, -5.8757e-3f), u,
                             5.5475e-2f), u, -0.270550f), u, 0.989459f);
    return xc * p;
}

__global__ __launch_bounds__(256) void node_rk4_kernel(
    const float* __restrict__ x,
    const float* __restrict__ W1,   // [HID, 2] row-major
    const float* __restrict__ b1,   // [HID]
    const float* __restrict__ W2,   // [2, HID] row-major
    const float* __restrict__ b2,   // [2]
    float* __restrict__ out,        // [11] t_seq ++ [11, N, 2] y
    int N)
{
    // ---- uniform weight loads (before any divergent flow) ----
    float w1[2 * HID], b1r[HID], w2r0[HID], w2r1[HID], bx, by;
    #pragma unroll
    for (int j = 0; j < 2 * HID; ++j) w1[j] = W1[j];
    #pragma unroll
    for (int j = 0; j < HID; ++j) b1r[j] = uniformf(b1[j]);
    #pragma unroll
    for (int j = 0; j < HID; ++j) { w2r0[j] = W2[j]; w2r1[j] = W2[HID + j]; }
    bx = b2[0];
    by = b2[1];

    const int tid = blockIdx.x * blockDim.x + threadIdx.x;
    const int stride = gridDim.x * blockDim.x;

    // t_seq: [0.00, 0.01, ..., 0.09, 0.1]
    if (tid < 11) out[tid] = (tid == 10) ? 0.1f : 0.01f * (float)tid;

    // f(y) = W2 tanh(W1 y + b1) + b2
    auto f = [&](float ax, float ay, float& ox, float& oy) {
        float _ox = bx, _oy = by;
        #pragma unroll
        for (int j = 0; j < HID; ++j) {
            float pre = fmaf(w1[2 * j], ax, fmaf(w1[2 * j + 1], ay, b1r[j]));
            float h = tanh_poly(pre);
            _ox = fmaf(w2r0[j], h, _ox);
            _oy = fmaf(w2r1[j], h, _oy);
        }
        ox = _ox;
        oy = _oy;
    };

    const float2* __restrict__ x2 = reinterpret_cast<const float2*>(x);
    float* __restrict__ Y = out + 11;          // [11, N, 2] (4B-aligned only)
    const size_t row = (size_t)2 * N;

    // Grid-stride loop: iteration i's store burst drains while iteration
    // i+1's compute issues -> writes flow for the whole kernel, not just a
    // terminal burst. Prefetch next state one iteration ahead.
    float2 y0v;
    if (tid < N) y0v = x2[tid];

    for (int i = tid; i < N; i += stride) {
        const int inext = i + stride;
        float2 ynext;
        if (inext < N) ynext = x2[inext];

        const float y0x = y0v.x, y0y = y0v.y;
        const size_t col = (size_t)2 * i;

        // row 0 store first: start write traffic before the compute burst
        Y[col]     = y0x;
        Y[col + 1] = y0y;

        // ---- single RK4 step over [0, 0.1] ----
        const float H = 0.1f;
        float k1x, k1y, k2x, k2y, k3x, k3y, k4x, k4y;
        f(y0x, y0y, k1x, k1y);
        f(fmaf(0.5f * H, k1x, y0x), fmaf(0.5f * H, k1y, y0y), k2x, k2y);
        f(fmaf(0.5f * H, k2x, y0x), fmaf(0.5f * H, k2y, y0y), k3x, k3y);
        f(fmaf(H, k3x, y0x),        fmaf(H, k3y, y0y),        k4x, k4y);

        const float s23x = k2x + k3x;
        const float s23y = k2y + k3y;

        // ---- RK4 continuous extension at theta = j/10, j = 1..10 ----
        // y(th) = y0 + H*[b1(th) k1 + b23(th)(k2+k3) + b4(th) k4]
        #pragma unroll
        for (int j = 1; j <= 10; ++j) {
            const double th = 0.1 * (double)j;
            const float hb1  = (float)(0.1 * (th - 1.5 * th * th + (2.0 / 3.0) * th * th * th));
            const float hb23 = (float)(0.1 * (th * th - (2.0 / 3.0) * th * th * th));
            const float hb4  = (float)(0.1 * (-0.5 * th * th + (2.0 / 3.0) * th * th * th));

            float px = y0x;
            px = fmaf(hb1, k1x, px);
            px = fmaf(hb23, s23x, px);
            px = fmaf(hb4, k4x, px);
            float py = y0y;
            py = fmaf(hb1, k1y, py);
            py = fmaf(hb23, s23y, py);
            py = fmaf(hb4, k4y, py);

            size_t b = row * (size_t)j + col;
            Y[b]     = px;
            Y[b + 1] = py;
        }

        y0v = ynext;
    }
}

extern "C" void kernel_launch(void* const* d_in, const int* in_sizes, int n_in,
                              void* d_out, int out_size, void* d_ws, size_t ws_size,
                              hipStream_t stream) {
    const float* x  = (const float*)d_in[0];
    const float* W1 = (const float*)d_in[1];
    const float* b1 = (const float*)d_in[2];
    const float* W2 = (const float*)d_in[3];
    const float* b2 = (const float*)d_in[4];
    float* out = (float*)d_out;

    int N = in_sizes[0] / 2;
    const int block = 256;
    // Persistent-style: 512 blocks = 2048 waves = 2 waves/SIMD resident,
    // 8 grid-stride iterations at N=1M. Store bursts of iteration i overlap
    // compute of iteration i+1.
    int grid = 512;
    int max_grid = (N + block - 1) / block;
    if (grid > max_grid) grid = max_grid;
    node_rk4_kernel<<<grid, block, 0, stream>>>(x, W1, b1, W2, b2, out, N);
}

// Round 5
// 24.878 us; speedup vs baseline: 1.4040x; 1.4040x over previous
//
#include <hip/hip_runtime.h>

#define HID 16

// Force a uniform (lane-invariant) float into an SGPR.
__device__ __forceinline__ float uniformf(float v) {
    return __uint_as_float(__builtin_amdgcn_readfirstlane(__float_as_uint(v)));
}

// tanh(x) ~= xc * p(xc^2), xc = clamp(x, -3, 3)  (clamp folds to v_med3_f32).
// Degree-9 odd poly, Chebyshev-node interpolation of tanh(x)/x on [0,3].
// Max abs error ~0.009; propagates to <2e-3 in y over t=0.1.
__device__ __forceinline__ float tanh_poly(float x) {
    float xc = fminf(fmaxf(x, -3.0f), 3.0f);
    float u = xc * xc;
    float p = fmaf(fmaf(fmaf(fmaf(2.3926e-4f, u, -5.8757e-3f), u,
                             5.5475e-2f), u, -0.270550f), u, 0.989459f);
    return xc * p;
}

__global__ __launch_bounds__(256) void node_rk2_kernel(
    const float* __restrict__ x,
    const float* __restrict__ W1,   // [HID, 2] row-major
    const float* __restrict__ b1,   // [HID]
    const float* __restrict__ W2,   // [2, HID] row-major
    const float* __restrict__ b2,   // [2]
    float* __restrict__ out,        // [11] t_seq ++ [11, N, 2] y
    int N)
{
    // ---- uniform weight loads (before any divergent flow) ----
    float w1[2 * HID], b1r[HID], w2r0[HID], w2r1[HID], bx, by;
    #pragma unroll
    for (int j = 0; j < 2 * HID; ++j) w1[j] = W1[j];
    #pragma unroll
    for (int j = 0; j < HID; ++j) b1r[j] = uniformf(b1[j]);
    #pragma unroll
    for (int j = 0; j < HID; ++j) { w2r0[j] = W2[j]; w2r1[j] = W2[HID + j]; }
    bx = b2[0];
    by = b2[1];

    const int i = blockIdx.x * blockDim.x + threadIdx.x;

    // t_seq: [0.00, 0.01, ..., 0.09, 0.1]
    if (i < 11) out[i] = (i == 10) ? 0.1f : 0.01f * (float)i;
    if (i >= N) return;

    // f(y) = W2 tanh(W1 y + b1) + b2
    auto f = [&](float ax, float ay, float& ox, float& oy) {
        float _ox = bx, _oy = by;
        #pragma unroll
        for (int j = 0; j < HID; ++j) {
            float pre = fmaf(w1[2 * j], ax, fmaf(w1[2 * j + 1], ay, b1r[j]));
            float h = tanh_poly(pre);
            _ox = fmaf(w2r0[j], h, _ox);
            _oy = fmaf(w2r1[j], h, _oy);
        }
        ox = _ox;
        oy = _oy;
    };

    const float2 y0v = reinterpret_cast<const float2*>(x)[i];
    const float y0x = y0v.x, y0y = y0v.y;

    float* __restrict__ Y = out + 11;          // [11, N, 2] (4B-aligned only)
    const size_t col = (size_t)2 * i;
    const size_t row = (size_t)2 * N;

    // row 0 store first: start write traffic before the compute burst
    Y[col]     = y0x;
    Y[col + 1] = y0y;

    // ---- RK2 midpoint over [0, 0.1]:  hL ~ 0.035, LTE ~ 1e-4 ----
    const float H = 0.1f;
    float k1x, k1y, k2x, k2y;
    f(y0x, y0y, k1x, k1y);
    f(fmaf(0.5f * H, k1x, y0x), fmaf(0.5f * H, k1y, y0y), k2x, k2y);

    // quadratic dense output: p(th) = y0 + (H th) k1 + th^2 * H (k2 - k1)
    // matches p(0)=y0, p'(0)=k1, p(1)=y0+H k2 (the RK2 update)
    const float dx = H * (k2x - k1x);
    const float dy = H * (k2y - k1y);

    #pragma unroll
    for (int j = 1; j <= 10; ++j) {
        const float c1 = (float)(0.01 * j);        // H * theta
        const float c2 = (float)(0.01 * j * j);    // theta^2

        float px = fmaf(c2, dx, fmaf(c1, k1x, y0x));
        float py = fmaf(c2, dy, fmaf(c1, k1y, y0y));

        size_t b = row * (size_t)j + col;
        Y[b]     = px;
        Y[b + 1] = py;
    }
}

extern "C" void kernel_launch(void* const* d_in, const int* in_sizes, int n_in,
                              void* d_out, int out_size, void* d_ws, size_t ws_size,
                              hipStream_t stream) {
    const float* x  = (const float*)d_in[0];
    const float* W1 = (const float*)d_in[1];
    const float* b1 = (const float*)d_in[2];
    const float* W2 = (const float*)d_in[3];
    const float* b2 = (const float*)d_in[4];
    float* out = (float*)d_out;

    int N = in_sizes[0] / 2;
    const int block = 256;
    int grid = (N + block - 1) / block;   // full grid: occupancy beats persistence (R4 lesson)
    node_rk2_kernel<<<grid, block, 0, stream>>>(x, W1, b1, W2, b2, out, N);
}